// Round 8
// baseline (433.175 us; speedup 1.0000x reference)
//
#include <hip/hip_runtime.h>
#include <math.h>

typedef _Float16 half8  __attribute__((ext_vector_type(8)));
typedef _Float16 half4v __attribute__((ext_vector_type(4)));
typedef float    f32x4  __attribute__((ext_vector_type(4)));

__device__ __forceinline__ _Float16 f2h(float f) { return (_Float16)f; }

__device__ __forceinline__ float tanh_fast(float x) {
    // 1 - 2/(e^{2x}+1); exact at +/-inf, ~1e-7 rel err. __expf -> v_exp.
    float e = __expf(2.f * x);
    return 1.f - 2.f / (e + 1.f);
}

#define LDSB (128 * 40)   // one 128x32 f16 tile, padded row stride 40

// C_part[zout][1024][ldc] (f16) = A[:, kb:kb+kLen] @ W[:, kb:kb+kLen]^T
// A: five 1024-wide f32 segments selected by global-k>>10.
// W: nsel=0 -> [W0 (k<w0cols, stride w0s) | W1 (stride w1s)], selected PER K-TILE;
//    nsel=1 -> W{0,1,2} selected by output-col block of 512 (each [512][1024]).
__device__ __forceinline__ void gemm_body(
    _Float16* __restrict__ sm,
    const float* A0, const float* A1, const float* A2p, const float* A3,
    const float* A4,
    const float* W0, const float* W1, const float* W2,
    int w0cols, int w0s, int w1s, int nsel,
    _Float16* __restrict__ Cpart, int ldc,
    int kb, int kLen, int ntile, int mtile, int zout)
{
    _Float16* smA = sm;             // [2][LDSB]
    _Float16* smW = sm + 2 * LDSB;  // [2][LDSB]
    const int tid  = threadIdx.x;
    const int lane = tid & 63;
    const int wid  = tid >> 6;
    const int wm   = wid >> 1, wn = wid & 1;
    const int m0   = mtile * 128;
    const int n0   = ntile * 128;
    const int nt   = kLen >> 5;
    const int srow = tid >> 3;         // 0..31
    const int scol = (tid & 7) << 2;   // 0..28
    const int fr   = lane & 15;
    const int kq   = lane >> 4;

    const float* wsel = nullptr;
    if (nsel) {
        int sel = n0 >> 9;
        const float* Wq = (sel == 0) ? W0 : (sel == 1) ? W1 : W2;
        wsel = Wq + (size_t)((n0 & 511) + srow) * 1024 + kb + scol;
    }

    f32x4 acc[4][4] = {};
    float4 va[4], vw[4];

    auto LOADA = [&](int lk) {
        int gk = kb + lk;
        int seg = gk >> 10;
        const float* ap = (seg == 0) ? A0 : (seg == 1) ? A1 : (seg == 2) ? A2p
                        : (seg == 3) ? A3 : A4;
        ap += (size_t)(m0 + srow) * 1024 + (gk & 1023) + scol;
        #pragma unroll
        for (int p = 0; p < 4; ++p)
            va[p] = *reinterpret_cast<const float4*>(ap + (size_t)p * 32 * 1024);
    };
    auto LOADW = [&](int lk) {
        const float* wp; int wstr;
        if (nsel) {
            wp = wsel + lk; wstr = 1024;
        } else {
            int gk = kb + lk;
            if (gk < w0cols) { wp = W0 + (size_t)(n0 + srow) * w0s + gk + scol;            wstr = w0s; }
            else             { wp = W1 + (size_t)(n0 + srow) * w1s + (gk - w0cols) + scol; wstr = w1s; }
        }
        #pragma unroll
        for (int p = 0; p < 4; ++p)
            vw[p] = *reinterpret_cast<const float4*>(wp + (size_t)p * 32 * wstr);
    };
    auto WRITEA = [&](int buf) {
        _Float16* d = smA + buf * LDSB;
        #pragma unroll
        for (int p = 0; p < 4; ++p) {
            half4v h = { f2h(va[p].x), f2h(va[p].y), f2h(va[p].z), f2h(va[p].w) };
            *reinterpret_cast<half4v*>(&d[(srow + p * 32) * 40 + scol]) = h;
        }
    };
    auto WRITEW = [&](int buf) {
        _Float16* d = smW + buf * LDSB;
        #pragma unroll
        for (int p = 0; p < 4; ++p) {
            half4v h = { f2h(vw[p].x), f2h(vw[p].y), f2h(vw[p].z), f2h(vw[p].w) };
            *reinterpret_cast<half4v*>(&d[(srow + p * 32) * 40 + scol]) = h;
        }
    };
    auto DOMFMA = [&](int buf) {
        half8 af[4], bf[4];
        _Float16* sA = smA + buf * LDSB;
        _Float16* sW = smW + buf * LDSB;
        #pragma unroll
        for (int i = 0; i < 4; ++i) {
            af[i] = *reinterpret_cast<const half8*>(&sA[(wm * 64 + i * 16 + fr) * 40 + kq * 8]);
            bf[i] = *reinterpret_cast<const half8*>(&sW[(wn * 64 + i * 16 + fr) * 40 + kq * 8]);
        }
        #pragma unroll
        for (int i = 0; i < 4; ++i)
            #pragma unroll
            for (int j = 0; j < 4; ++j)
                acc[i][j] = __builtin_amdgcn_mfma_f32_16x16x32_f16(af[i], bf[j], acc[i][j], 0, 0, 0);
    };

    LOADA(0); LOADW(0);
    WRITEA(0); WRITEW(0);
    __syncthreads();
    int cur = 0;
    for (int it = 0; it < nt - 1; ++it) {
        LOADA((it + 1) * 32);     // next-tile loads in flight under MFMA
        LOADW((it + 1) * 32);
        DOMFMA(cur);
        WRITEA(cur ^ 1);
        WRITEW(cur ^ 1);
        __syncthreads();
        cur ^= 1;
    }
    DOMFMA(cur);

    _Float16* cp = Cpart + (size_t)zout * 1024ull * (size_t)ldc;
    #pragma unroll
    for (int j = 0; j < 4; ++j) {
        int nc = n0 + wn * 64 + j * 16 + fr;
        #pragma unroll
        for (int i = 0; i < 4; ++i) {
            int rb = m0 + wm * 64 + i * 16 + kq * 4;
            #pragma unroll
            for (int r = 0; r < 4; ++r)
                cp[(size_t)(rb + r) * ldc + nc] = (_Float16)acc[i][j][r];
        }
    }
}

__global__ __launch_bounds__(256) void gemm_hf(
    const float* A0, const float* A1, const float* A2p, const float* A3,
    const float* A4,
    const float* W0, const float* W1, const float* W2,
    int w0cols, int w0s, int w1s, int nsel,
    _Float16* Cpart, int ldc, int kLen, int zbase)
{
    __shared__ _Float16 sm[4 * LDSB];
    gemm_body(sm, A0, A1, A2p, A3, A4, W0, W1, W2, w0cols, w0s, w1s, nsel,
              Cpart, ldc, blockIdx.z * kLen, kLen,
              blockIdx.x, blockIdx.y, zbase + blockIdx.z);
}

// ---------------- attention, split into 3 single-phase streaming kernels ----------------
// Row space per batch b: rows [0,16)=attr, [16,52)=obj, [52,116)=rela.
// scg/wgtg layout: [B][128] f32 (slots 0..115 used).

// One WAVE per (b, row): 1024*116 waves = 29696 blocks x 4 waves. No LDS, no barriers.
__global__ __launch_bounds__(256) void att_scores(
    const float* __restrict__ p_attr, const float* __restrict__ p_obj,
    const float* __restrict__ p_rela,
    const _Float16* __restrict__ q16,     // [2][B][1536]
    const float* __restrict__ attr_bq, const float* __restrict__ obj_bq,
    const float* __restrict__ rela_bq,
    const float* __restrict__ attr_wa, const float* __restrict__ obj_wa,
    const float* __restrict__ rela_wa,
    const float* __restrict__ attr_ba, const float* __restrict__ obj_ba,
    const float* __restrict__ rela_ba,
    float* __restrict__ scg)              // [B][128]
{
    const unsigned gw = blockIdx.x * 4u + (threadIdx.x >> 6);
    const int lane = threadIdx.x & 63;
    const unsigned b = gw / 116u;
    const int r = (int)(gw - b * 116u);
    const float* pf; const float* bq; const float* wa; const float* ba;
    int l, moff, scoff, L;
    if (r < 16)      { pf = p_attr; bq = attr_bq; wa = attr_wa; ba = attr_ba; l = r;      moff = 0;    scoff = 0;  L = 16; }
    else if (r < 52) { pf = p_obj;  bq = obj_bq;  wa = obj_wa;  ba = obj_ba;  l = r - 16; moff = 512;  scoff = 16; L = 36; }
    else             { pf = p_rela; bq = rela_bq; wa = rela_wa; ba = rela_ba; l = r - 52; moff = 1024; scoff = 52; L = 64; }

    const float4* pf4 = reinterpret_cast<const float4*>(pf) + ((size_t)b * L + l) * 128 + lane * 2;
    float4 a0 = pf4[0];
    float4 a1 = pf4[1];
    const _Float16* qb = q16 + (size_t)b * 1536 + moff + lane * 8;
    half8 hq0 = *reinterpret_cast<const half8*>(qb);
    half8 hq1 = *reinterpret_cast<const half8*>(qb + 1536ull * 1024);
    const float4* bq4 = reinterpret_cast<const float4*>(bq) + lane * 2;
    const float4* wa4 = reinterpret_cast<const float4*>(wa) + lane * 2;
    float4 b0 = bq4[0], b1 = bq4[1];
    float4 w0 = wa4[0], w1 = wa4[1];

    float s = tanh_fast(a0.x + (float)hq0[0] + (float)hq1[0] + b0.x) * w0.x
            + tanh_fast(a0.y + (float)hq0[1] + (float)hq1[1] + b0.y) * w0.y
            + tanh_fast(a0.z + (float)hq0[2] + (float)hq1[2] + b0.z) * w0.z
            + tanh_fast(a0.w + (float)hq0[3] + (float)hq1[3] + b0.w) * w0.w
            + tanh_fast(a1.x + (float)hq0[4] + (float)hq1[4] + b1.x) * w1.x
            + tanh_fast(a1.y + (float)hq0[5] + (float)hq1[5] + b1.y) * w1.y
            + tanh_fast(a1.z + (float)hq0[6] + (float)hq1[6] + b1.z) * w1.z
            + tanh_fast(a1.w + (float)hq0[7] + (float)hq1[7] + b1.w) * w1.w;
    #pragma unroll
    for (int off = 32; off >= 1; off >>= 1) s += __shfl_xor(s, off);
    if (lane == 0) scg[(size_t)b * 128 + scoff + l] = s + ba[0];
}

// One block per b; wave wid handles modality wid (softmax * mask / renorm).
__global__ __launch_bounds__(256) void att_softmax(
    const float* __restrict__ scg,
    const float* __restrict__ attr_masks, const float* __restrict__ att_masks,
    const float* __restrict__ rela_masks,
    float* __restrict__ wgtg)
{
    const int b = blockIdx.x;
    const int wid = threadIdx.x >> 6, lane = threadIdx.x & 63;
    if (wid >= 3) return;
    const int L     = (wid == 0) ? 16 : (wid == 1) ? 36 : 64;
    const int scoff = (wid == 0) ? 0  : (wid == 1) ? 16 : 52;
    const float* mask = (wid == 0) ? attr_masks : (wid == 1) ? att_masks : rela_masks;
    float v = (lane < L) ? scg[(size_t)b * 128 + scoff + lane] : -1e30f;
    float m = v;
    #pragma unroll
    for (int off = 32; off >= 1; off >>= 1) m = fmaxf(m, __shfl_xor(m, off));
    float e = (lane < L) ? __expf(v - m) : 0.f;
    float sum = e;
    #pragma unroll
    for (int off = 32; off >= 1; off >>= 1) sum += __shfl_xor(sum, off);
    float w = e / sum;
    float wm = (lane < L) ? w * mask[(size_t)b * L + lane] : 0.f;
    float s2 = wm;
    #pragma unroll
    for (int off = 32; off >= 1; off >>= 1) s2 += __shfl_xor(s2, off);
    if (lane < L) wgtg[(size_t)b * 128 + scoff + lane] = wm / (s2 + 1e-8f);
}

// Weighted feature sum, single phase. mod = bid%3 (interleaved), b = bid/3.
template<int L>
__device__ __forceinline__ void wsum_mod(
    const float* __restrict__ feats, const float* __restrict__ wgt,
    float* __restrict__ outa, int b)
{
    const int d0 = threadIdx.x * 4;
    const float* fp = feats + (size_t)b * L * 1024 + d0;
    f32x4 acc = {0.f, 0.f, 0.f, 0.f};
    constexpr int NFULL = L / 8;
    float4 vA[8], vB[8];
    #pragma unroll
    for (int j = 0; j < 8; ++j)
        vA[j] = *reinterpret_cast<const float4*>(fp + (size_t)j * 1024);
    #pragma unroll
    for (int g = 0; g < NFULL; ++g) {
        float4* cur = (g & 1) ? vB : vA;
        float4* nxt = (g & 1) ? vA : vB;
        if (g + 1 < NFULL) {
            #pragma unroll
            for (int j = 0; j < 8; ++j)
                nxt[j] = *reinterpret_cast<const float4*>(fp + (size_t)((g + 1) * 8 + j) * 1024);
        }
        #pragma unroll
        for (int j = 0; j < 8; ++j) {
            const float w = wgt[g * 8 + j];
            acc[0] += w * cur[j].x; acc[1] += w * cur[j].y;
            acc[2] += w * cur[j].z; acc[3] += w * cur[j].w;
        }
    }
    #pragma unroll
    for (int lg = NFULL * 8; lg < L; ++lg) {
        float4 v = *reinterpret_cast<const float4*>(fp + (size_t)lg * 1024);
        const float w = wgt[lg];
        acc[0] += w * v.x; acc[1] += w * v.y; acc[2] += w * v.z; acc[3] += w * v.w;
    }
    float4 o; o.x = acc[0]; o.y = acc[1]; o.z = acc[2]; o.w = acc[3];
    *reinterpret_cast<float4*>(outa + (size_t)b * 1024 + d0) = o;
}

__global__ __launch_bounds__(256) void att_wsum(
    const float* __restrict__ attr_feats, const float* __restrict__ obj_feats,
    const float* __restrict__ rela_feats,
    const float* __restrict__ wgtg,      // [B][128]
    float* __restrict__ a32)             // [3][B][1024]
{
    const int bid = blockIdx.x;
    const int mod = bid % 3;
    const int b   = bid / 3;
    if (mod == 0)
        wsum_mod<16>(attr_feats, wgtg + (size_t)b * 128 + 0,  a32, b);
    else if (mod == 1)
        wsum_mod<36>(obj_feats,  wgtg + (size_t)b * 128 + 16, a32 + 1024ull * 1024, b);
    else
        wsum_mod<64>(rela_feats, wgtg + (size_t)b * 128 + 52, a32 + 2ull * 1024 * 1024, b);
}

// LSTM elementwise from nz f16 gate partials + biases.
__global__ __launch_bounds__(256) void lstm4(
    const _Float16* __restrict__ g, size_t zstride, int nz,
    const float* __restrict__ bih, const float* __restrict__ bhh,
    const float* __restrict__ c_prev,
    float* __restrict__ hA, float* __restrict__ hB,
    float* __restrict__ c_out)
{
    int idx = blockIdx.x * 256 + threadIdx.x;  // [0, 1M)
    int b = idx >> 10, r = idx & 1023;
    size_t base = (size_t)b * 4096;
    float gi = bih[r]        + bhh[r];
    float gf = bih[1024 + r] + bhh[1024 + r];
    float gg = bih[2048 + r] + bhh[2048 + r];
    float go = bih[3072 + r] + bhh[3072 + r];
    for (int z = 0; z < nz; ++z) {
        const _Float16* gz = g + (size_t)z * zstride + base;
        gi += (float)gz[r];
        gf += (float)gz[1024 + r];
        gg += (float)gz[2048 + r];
        go += (float)gz[3072 + r];
    }
    float si = 1.f / (1.f + __expf(-gi));
    float sf = 1.f / (1.f + __expf(-gf));
    float so = 1.f / (1.f + __expf(-go));
    float c2 = sf * c_prev[idx] + si * tanh_fast(gg);
    float h2 = so * tanh_fast(c2);
    hA[idx] = h2;
    if (hB) hB[idx] = h2;
    c_out[idx] = c2;
}

extern "C" void kernel_launch(void* const* d_in, const int* in_sizes, int n_in,
                              void* d_out, int out_size, void* d_ws, size_t ws_size,
                              hipStream_t stream)
{
    const size_t BR = 1024ull * 1024ull;
    const float* xt         = (const float*)d_in[0];
    const float* fc         = (const float*)d_in[1];
    const float* state_h    = (const float*)d_in[2];
    const float* state_c    = (const float*)d_in[3];
    const float* attr_feats = (const float*)d_in[4];
    const float* obj_feats  = (const float*)d_in[5];
    const float* rela_feats = (const float*)d_in[6];
    const float* p_attr     = (const float*)d_in[7];
    const float* p_obj      = (const float*)d_in[8];
    const float* p_rela     = (const float*)d_in[9];
    const float* attr_masks = (const float*)d_in[10];
    const float* att_masks  = (const float*)d_in[11];
    const float* rela_masks = (const float*)d_in[12];
    const float* att_Wih    = (const float*)d_in[13];
    const float* att_Whh    = (const float*)d_in[14];
    const float* att_bih    = (const float*)d_in[15];
    const float* att_bhh    = (const float*)d_in[16];
    const float* lang_Wih   = (const float*)d_in[17];
    const float* lang_Whh   = (const float*)d_in[18];
    const float* lang_bih   = (const float*)d_in[19];
    const float* lang_bhh   = (const float*)d_in[20];
    const float* attr_Wq    = (const float*)d_in[21];
    const float* attr_bq    = (const float*)d_in[22];
    const float* attr_wa    = (const float*)d_in[23];
    const float* attr_ba    = (const float*)d_in[24];
    const float* obj_Wq     = (const float*)d_in[25];
    const float* obj_bq     = (const float*)d_in[26];
    const float* obj_wa     = (const float*)d_in[27];
    const float* obj_ba     = (const float*)d_in[28];
    const float* rela_Wq    = (const float*)d_in[29];
    const float* rela_bq    = (const float*)d_in[30];
    const float* rela_wa    = (const float*)d_in[31];
    const float* rela_ba    = (const float*)d_in[32];

    float* out = (float*)d_out;
    const float* h0 = state_h;            // state_h[0]
    const float* h1 = state_h + BR;       // state_h[1] (prev_h)
    float* h_att = out + BR;              // h_att output slot, reused as GEMM input
    // Scratch inside out slot 0 (fully rewritten by final lstm4):
    float* scg  = out;                    // [1024][128]
    float* wgtg = out + 1024 * 128;       // [1024][128]

    // Workspace: primary (>=50MiB): 4 gate-partial slots; fallback: 2 slots (34MiB, proven).
    const bool big = ws_size >= 52428800ull;
    const int gslots = big ? 4 : 2;
    _Float16* g16 = (_Float16*)d_ws;                         // [gslots][1024][4096] f16
    _Float16* q16 = g16 + (size_t)gslots * 4ull * BR;        // [2][1024][1536] f16
    float*    a32 = (float*)(q16 + 2ull * 1536 * 1024);      // [3][1024][1024] f32
    float* a_attr = a32;
    float* a_obj  = a32 + BR;
    float* a_rela = a32 + 2 * BR;

    dim3 blk(256);
    const int zsplit = big ? 4 : 2;

    // 1) att-LSTM gates: A = [h1 | fc | xt | h0], K=4096 (Wih 3072 cols, then Whh)
    gemm_hf<<<dim3(32, 8, zsplit), blk, 0, stream>>>(
        h1, fc, xt, h0, h0, att_Wih, att_Whh, att_Whh,
        3072, 3072, 1024, 0, g16, 4096, 4096 / zsplit, 0);
    // 2) att-LSTM elementwise -> h_att (out[BR]), c_att (out[3BR])
    lstm4<<<dim3(4096), blk, 0, stream>>>(
        g16, 4ull * BR, gslots, att_bih, att_bhh, state_c,
        h_att, nullptr, out + 3 * BR);
    // 3) fused q = h_att @ [Wq_attr;Wq_obj;Wq_rela]^T, N=1536, K=1024 split 2x512
    gemm_hf<<<dim3(12, 8, 2), blk, 0, stream>>>(
        h_att, h_att, h_att, h_att, h_att,
        attr_Wq, obj_Wq, rela_Wq, 0, 1024, 1024, 1,
        q16, 1536, 512, 0);
    // 4a) scores: one wave per (b,row); 1024*116/4 = 29696 blocks
    att_scores<<<dim3(29696), blk, 0, stream>>>(
        p_attr, p_obj, p_rela, q16,
        attr_bq, obj_bq, rela_bq, attr_wa, obj_wa, rela_wa,
        attr_ba, obj_ba, rela_ba, scg);
    // 4b) softmax * mask / renorm
    att_softmax<<<dim3(1024), blk, 0, stream>>>(
        scg, attr_masks, att_masks, rela_masks, wgtg);
    // 4c) weighted sums
    att_wsum<<<dim3(3072), blk, 0, stream>>>(
        attr_feats, obj_feats, rela_feats, wgtg, a32);
    // 5) lang-LSTM gates: A = [h_att | a_attr | a_obj | a_rela | h1], K=5120
    gemm_hf<<<dim3(32, 8, zsplit), blk, 0, stream>>>(
        h_att, a_attr, a_obj, a_rela, h1,
        lang_Wih, lang_Whh, lang_Whh, 4096, 4096, 1024, 0,
        g16, 4096, 5120 / zsplit, 0);
    // 6) lang-LSTM elementwise -> output (out[0]), h_lang (out[2BR]), c_lang (out[4BR])
    lstm4<<<dim3(4096), blk, 0, stream>>>(
        g16, 4ull * BR, gslots, lang_bih, lang_bhh, state_c + BR,
        out, out + 2 * BR, out + 4 * BR);
}

// Round 9
// 428.840 us; speedup vs baseline: 1.0101x; 1.0101x over previous
//
#include <hip/hip_runtime.h>
#include <math.h>

typedef _Float16 half8  __attribute__((ext_vector_type(8)));
typedef _Float16 half4v __attribute__((ext_vector_type(4)));
typedef float    f32x4  __attribute__((ext_vector_type(4)));

__device__ __forceinline__ _Float16 f2h(float f) { return (_Float16)f; }

__device__ __forceinline__ float tanh_fast(float x) {
    float e = __expf(2.f * x);
    return 1.f - 2.f / (e + 1.f);
}

#define LDSB (128 * 40)   // one 128x32 f16 tile, padded row stride 40

// C_part[zout][1024][ldc] (f16) = A[:, kb:kb+kLen] @ W[:, kb:kb+kLen]^T
__device__ __forceinline__ void gemm_body(
    _Float16* __restrict__ sm,
    const float* A0, const float* A1, const float* A2p, const float* A3,
    const float* A4,
    const float* W0, const float* W1, const float* W2,
    int w0cols, int w0s, int w1s, int nsel,
    _Float16* __restrict__ Cpart, int ldc,
    int kb, int kLen, int ntile, int mtile, int zout)
{
    _Float16* smA = sm;             // [2][LDSB]
    _Float16* smW = sm + 2 * LDSB;  // [2][LDSB]
    const int tid  = threadIdx.x;
    const int lane = tid & 63;
    const int wid  = tid >> 6;
    const int wm   = wid >> 1, wn = wid & 1;
    const int m0   = mtile * 128;
    const int n0   = ntile * 128;
    const int nt   = kLen >> 5;
    const int srow = tid >> 3;         // 0..31
    const int scol = (tid & 7) << 2;   // 0..28
    const int fr   = lane & 15;
    const int kq   = lane >> 4;

    const float* wsel = nullptr;
    if (nsel) {
        int sel = n0 >> 9;
        const float* Wq = (sel == 0) ? W0 : (sel == 1) ? W1 : W2;
        wsel = Wq + (size_t)((n0 & 511) + srow) * 1024 + kb + scol;
    }

    f32x4 acc[4][4] = {};
    float4 va[4], vw[4];

    auto LOADA = [&](int lk) {
        int gk = kb + lk;
        int seg = gk >> 10;
        const float* ap = (seg == 0) ? A0 : (seg == 1) ? A1 : (seg == 2) ? A2p
                        : (seg == 3) ? A3 : A4;
        ap += (size_t)(m0 + srow) * 1024 + (gk & 1023) + scol;
        #pragma unroll
        for (int p = 0; p < 4; ++p)
            va[p] = *reinterpret_cast<const float4*>(ap + (size_t)p * 32 * 1024);
    };
    auto LOADW = [&](int lk) {
        const float* wp; int wstr;
        if (nsel) {
            wp = wsel + lk; wstr = 1024;
        } else {
            int gk = kb + lk;
            if (gk < w0cols) { wp = W0 + (size_t)(n0 + srow) * w0s + gk + scol;            wstr = w0s; }
            else             { wp = W1 + (size_t)(n0 + srow) * w1s + (gk - w0cols) + scol; wstr = w1s; }
        }
        #pragma unroll
        for (int p = 0; p < 4; ++p)
            vw[p] = *reinterpret_cast<const float4*>(wp + (size_t)p * 32 * wstr);
    };
    auto WRITEA = [&](int buf) {
        _Float16* d = smA + buf * LDSB;
        #pragma unroll
        for (int p = 0; p < 4; ++p) {
            half4v h = { f2h(va[p].x), f2h(va[p].y), f2h(va[p].z), f2h(va[p].w) };
            *reinterpret_cast<half4v*>(&d[(srow + p * 32) * 40 + scol]) = h;
        }
    };
    auto WRITEW = [&](int buf) {
        _Float16* d = smW + buf * LDSB;
        #pragma unroll
        for (int p = 0; p < 4; ++p) {
            half4v h = { f2h(vw[p].x), f2h(vw[p].y), f2h(vw[p].z), f2h(vw[p].w) };
            *reinterpret_cast<half4v*>(&d[(srow + p * 32) * 40 + scol]) = h;
        }
    };
    auto DOMFMA = [&](int buf) {
        half8 af[4], bf[4];
        _Float16* sA = smA + buf * LDSB;
        _Float16* sW = smW + buf * LDSB;
        #pragma unroll
        for (int i = 0; i < 4; ++i) {
            af[i] = *reinterpret_cast<const half8*>(&sA[(wm * 64 + i * 16 + fr) * 40 + kq * 8]);
            bf[i] = *reinterpret_cast<const half8*>(&sW[(wn * 64 + i * 16 + fr) * 40 + kq * 8]);
        }
        #pragma unroll
        for (int i = 0; i < 4; ++i)
            #pragma unroll
            for (int j = 0; j < 4; ++j)
                acc[i][j] = __builtin_amdgcn_mfma_f32_16x16x32_f16(af[i], bf[j], acc[i][j], 0, 0, 0);
    };

    LOADA(0); LOADW(0);
    WRITEA(0); WRITEW(0);
    __syncthreads();
    int cur = 0;
    for (int it = 0; it < nt - 1; ++it) {
        LOADA((it + 1) * 32);
        LOADW((it + 1) * 32);
        DOMFMA(cur);
        WRITEA(cur ^ 1);
        WRITEW(cur ^ 1);
        __syncthreads();
        cur ^= 1;
    }
    DOMFMA(cur);

    _Float16* cp = Cpart + (size_t)zout * 1024ull * (size_t)ldc;
    #pragma unroll
    for (int j = 0; j < 4; ++j) {
        int nc = n0 + wn * 64 + j * 16 + fr;
        #pragma unroll
        for (int i = 0; i < 4; ++i) {
            int rb = m0 + wm * 64 + i * 16 + kq * 4;
            #pragma unroll
            for (int r = 0; r < 4; ++r)
                cp[(size_t)(rb + r) * ldc + nc] = (_Float16)acc[i][j][r];
        }
    }
}

// 3D-grid version (q-GEMM: small, no swizzle)
__global__ __launch_bounds__(256) void gemm_hf(
    const float* A0, const float* A1, const float* A2p, const float* A3,
    const float* A4,
    const float* W0, const float* W1, const float* W2,
    int w0cols, int w0s, int w1s, int nsel,
    _Float16* Cpart, int ldc, int kLen, int zbase)
{
    __shared__ _Float16 sm[4 * LDSB];
    gemm_body(sm, A0, A1, A2p, A3, A4, W0, W1, W2, w0cols, w0s, w1s, nsel,
              Cpart, ldc, blockIdx.z * kLen, kLen,
              blockIdx.x, blockIdx.y, zbase + blockIdx.z);
}

// Flat-grid XCD-swizzled version: all 8 m-blocks of one (n,z) group land on the
// same XCD (bid%8), making the shared 512KB W-panel L2-resident.
// grid = 256*zsplit blocks (bijective: xcd in [0,8), grpPerXcd = 4*zsplit, m in [0,8)).
__global__ __launch_bounds__(256) void gemm_hf_swz(
    const float* A0, const float* A1, const float* A2p, const float* A3,
    const float* A4,
    const float* W0, const float* W1, const float* W2,
    int w0cols, int w0s, int w1s,
    _Float16* Cpart, int ldc, int kLen, int zsplit)
{
    __shared__ _Float16 sm[4 * LDSB];
    const int bid = blockIdx.x;
    const int xcd = bid & 7;
    const int j   = bid >> 3;                    // [0, 32*zsplit)
    const int grp = xcd * (zsplit * 4) + (j >> 3);  // (n,z) group, [0, 32*zsplit)
    const int mtile = j & 7;
    const int ntile = grp / zsplit;              // [0, 32)
    const int z     = grp % zsplit;
    gemm_body(sm, A0, A1, A2p, A3, A4, W0, W1, W2, w0cols, w0s, w1s, 0,
              Cpart, ldc, z * kLen, kLen, ntile, mtile, z);
}

// ---------------- attention: scores (one wave per row), then softmax+wsum ----------------
// Row space per b: [0,16)=attr, [16,52)=obj, [52,116)=rela. scg: [B][128] f32.

__global__ __launch_bounds__(256) void att_scores(
    const float* __restrict__ p_attr, const float* __restrict__ p_obj,
    const float* __restrict__ p_rela,
    const _Float16* __restrict__ q16,     // [2][B][1536]
    const float* __restrict__ attr_bq, const float* __restrict__ obj_bq,
    const float* __restrict__ rela_bq,
    const float* __restrict__ attr_wa, const float* __restrict__ obj_wa,
    const float* __restrict__ rela_wa,
    const float* __restrict__ attr_ba, const float* __restrict__ obj_ba,
    const float* __restrict__ rela_ba,
    float* __restrict__ scg)              // [B][128]
{
    const unsigned gw = blockIdx.x * 4u + (threadIdx.x >> 6);
    const int lane = threadIdx.x & 63;
    const unsigned b = gw / 116u;
    const int r = (int)(gw - b * 116u);
    const float* pf; const float* bq; const float* wa; const float* ba;
    int l, moff, scoff, L;
    if (r < 16)      { pf = p_attr; bq = attr_bq; wa = attr_wa; ba = attr_ba; l = r;      moff = 0;    scoff = 0;  L = 16; }
    else if (r < 52) { pf = p_obj;  bq = obj_bq;  wa = obj_wa;  ba = obj_ba;  l = r - 16; moff = 512;  scoff = 16; L = 36; }
    else             { pf = p_rela; bq = rela_bq; wa = rela_wa; ba = rela_ba; l = r - 52; moff = 1024; scoff = 52; L = 64; }

    const float4* pf4 = reinterpret_cast<const float4*>(pf) + ((size_t)b * L + l) * 128 + lane * 2;
    float4 a0 = pf4[0];
    float4 a1 = pf4[1];
    const _Float16* qb = q16 + (size_t)b * 1536 + moff + lane * 8;
    half8 hq0 = *reinterpret_cast<const half8*>(qb);
    half8 hq1 = *reinterpret_cast<const half8*>(qb + 1536ull * 1024);
    const float4* bq4 = reinterpret_cast<const float4*>(bq) + lane * 2;
    const float4* wa4 = reinterpret_cast<const float4*>(wa) + lane * 2;
    float4 b0 = bq4[0], b1 = bq4[1];
    float4 w0 = wa4[0], w1 = wa4[1];

    float s = tanh_fast(a0.x + (float)hq0[0] + (float)hq1[0] + b0.x) * w0.x
            + tanh_fast(a0.y + (float)hq0[1] + (float)hq1[1] + b0.y) * w0.y
            + tanh_fast(a0.z + (float)hq0[2] + (float)hq1[2] + b0.z) * w0.z
            + tanh_fast(a0.w + (float)hq0[3] + (float)hq1[3] + b0.w) * w0.w
            + tanh_fast(a1.x + (float)hq0[4] + (float)hq1[4] + b1.x) * w1.x
            + tanh_fast(a1.y + (float)hq0[5] + (float)hq1[5] + b1.y) * w1.y
            + tanh_fast(a1.z + (float)hq0[6] + (float)hq1[6] + b1.z) * w1.z
            + tanh_fast(a1.w + (float)hq0[7] + (float)hq1[7] + b1.w) * w1.w;
    #pragma unroll
    for (int off = 32; off >= 1; off >>= 1) s += __shfl_xor(s, off);
    if (lane == 0) scg[(size_t)b * 128 + scoff + l] = s + ba[0];
}

// softmax (in-block, wave 0) + weighted feature sum. mod = bid%3, b = bid/3.
template<int L>
__device__ __forceinline__ void wsum_mod(
    const float* __restrict__ feats, const float* __restrict__ scg_b,
    const float* __restrict__ mask_b,
    float* __restrict__ outa, int b, float* wgt)
{
    const int tid = threadIdx.x;
    if (tid < 64) {
        float v = (tid < L) ? scg_b[tid] : -1e30f;
        float m = v;
        #pragma unroll
        for (int off = 32; off >= 1; off >>= 1) m = fmaxf(m, __shfl_xor(m, off));
        float e = (tid < L) ? __expf(v - m) : 0.f;
        float sum = e;
        #pragma unroll
        for (int off = 32; off >= 1; off >>= 1) sum += __shfl_xor(sum, off);
        float w = e / sum;
        float wm = (tid < L) ? w * mask_b[tid] : 0.f;
        float s2 = wm;
        #pragma unroll
        for (int off = 32; off >= 1; off >>= 1) s2 += __shfl_xor(s2, off);
        wgt[tid] = wm / (s2 + 1e-8f);
    }
    __syncthreads();

    const int d0 = tid * 4;
    const float* fp = feats + (size_t)b * L * 1024 + d0;
    f32x4 acc = {0.f, 0.f, 0.f, 0.f};
    constexpr int NFULL = L / 8;
    float4 vA[8], vB[8];
    #pragma unroll
    for (int j = 0; j < 8; ++j)
        vA[j] = *reinterpret_cast<const float4*>(fp + (size_t)j * 1024);
    #pragma unroll
    for (int g = 0; g < NFULL; ++g) {
        float4* cur = (g & 1) ? vB : vA;
        float4* nxt = (g & 1) ? vA : vB;
        if (g + 1 < NFULL) {
            #pragma unroll
            for (int j = 0; j < 8; ++j)
                nxt[j] = *reinterpret_cast<const float4*>(fp + (size_t)((g + 1) * 8 + j) * 1024);
        }
        #pragma unroll
        for (int j = 0; j < 8; ++j) {
            const float w = wgt[g * 8 + j];
            acc[0] += w * cur[j].x; acc[1] += w * cur[j].y;
            acc[2] += w * cur[j].z; acc[3] += w * cur[j].w;
        }
    }
    #pragma unroll
    for (int lg = NFULL * 8; lg < L; ++lg) {
        float4 v = *reinterpret_cast<const float4*>(fp + (size_t)lg * 1024);
        const float w = wgt[lg];
        acc[0] += w * v.x; acc[1] += w * v.y; acc[2] += w * v.z; acc[3] += w * v.w;
    }
    float4 o; o.x = acc[0]; o.y = acc[1]; o.z = acc[2]; o.w = acc[3];
    *reinterpret_cast<float4*>(outa + (size_t)b * 1024 + d0) = o;
}

__global__ __launch_bounds__(256) void att_wsum(
    const float* __restrict__ attr_feats, const float* __restrict__ obj_feats,
    const float* __restrict__ rela_feats,
    const float* __restrict__ attr_masks, const float* __restrict__ att_masks,
    const float* __restrict__ rela_masks,
    const float* __restrict__ scg,       // [B][128]
    float* __restrict__ a32)             // [3][B][1024]
{
    __shared__ float wgt[64];
    const int bid = blockIdx.x;
    const int mod = bid % 3;
    const int b   = bid / 3;
    if (mod == 0)
        wsum_mod<16>(attr_feats, scg + (size_t)b * 128 + 0,  attr_masks + (size_t)b * 16,
                     a32, b, wgt);
    else if (mod == 1)
        wsum_mod<36>(obj_feats,  scg + (size_t)b * 128 + 16, att_masks + (size_t)b * 36,
                     a32 + 1024ull * 1024, b, wgt);
    else
        wsum_mod<64>(rela_feats, scg + (size_t)b * 128 + 52, rela_masks + (size_t)b * 64,
                     a32 + 2ull * 1024 * 1024, b, wgt);
}

// LSTM elementwise from nz f16 gate partials + biases.
__global__ __launch_bounds__(256) void lstm4(
    const _Float16* __restrict__ g, size_t zstride, int nz,
    const float* __restrict__ bih, const float* __restrict__ bhh,
    const float* __restrict__ c_prev,
    float* __restrict__ hA, float* __restrict__ hB,
    float* __restrict__ c_out)
{
    int idx = blockIdx.x * 256 + threadIdx.x;  // [0, 1M)
    int b = idx >> 10, r = idx & 1023;
    size_t base = (size_t)b * 4096;
    float gi = bih[r]        + bhh[r];
    float gf = bih[1024 + r] + bhh[1024 + r];
    float gg = bih[2048 + r] + bhh[2048 + r];
    float go = bih[3072 + r] + bhh[3072 + r];
    for (int z = 0; z < nz; ++z) {
        const _Float16* gz = g + (size_t)z * zstride + base;
        gi += (float)gz[r];
        gf += (float)gz[1024 + r];
        gg += (float)gz[2048 + r];
        go += (float)gz[3072 + r];
    }
    float si = 1.f / (1.f + __expf(-gi));
    float sf = 1.f / (1.f + __expf(-gf));
    float so = 1.f / (1.f + __expf(-go));
    float c2 = sf * c_prev[idx] + si * tanh_fast(gg);
    float h2 = so * tanh_fast(c2);
    hA[idx] = h2;
    if (hB) hB[idx] = h2;
    c_out[idx] = c2;
}

extern "C" void kernel_launch(void* const* d_in, const int* in_sizes, int n_in,
                              void* d_out, int out_size, void* d_ws, size_t ws_size,
                              hipStream_t stream)
{
    const size_t BR = 1024ull * 1024ull;
    const float* xt         = (const float*)d_in[0];
    const float* fc         = (const float*)d_in[1];
    const float* state_h    = (const float*)d_in[2];
    const float* state_c    = (const float*)d_in[3];
    const float* attr_feats = (const float*)d_in[4];
    const float* obj_feats  = (const float*)d_in[5];
    const float* rela_feats = (const float*)d_in[6];
    const float* p_attr     = (const float*)d_in[7];
    const float* p_obj      = (const float*)d_in[8];
    const float* p_rela     = (const float*)d_in[9];
    const float* attr_masks = (const float*)d_in[10];
    const float* att_masks  = (const float*)d_in[11];
    const float* rela_masks = (const float*)d_in[12];
    const float* att_Wih    = (const float*)d_in[13];
    const float* att_Whh    = (const float*)d_in[14];
    const float* att_bih    = (const float*)d_in[15];
    const float* att_bhh    = (const float*)d_in[16];
    const float* lang_Wih   = (const float*)d_in[17];
    const float* lang_Whh   = (const float*)d_in[18];
    const float* lang_bih   = (const float*)d_in[19];
    const float* lang_bhh   = (const float*)d_in[20];
    const float* attr_Wq    = (const float*)d_in[21];
    const float* attr_bq    = (const float*)d_in[22];
    const float* attr_wa    = (const float*)d_in[23];
    const float* attr_ba    = (const float*)d_in[24];
    const float* obj_Wq     = (const float*)d_in[25];
    const float* obj_bq     = (const float*)d_in[26];
    const float* obj_wa     = (const float*)d_in[27];
    const float* obj_ba     = (const float*)d_in[28];
    const float* rela_Wq    = (const float*)d_in[29];
    const float* rela_bq    = (const float*)d_in[30];
    const float* rela_wa    = (const float*)d_in[31];
    const float* rela_ba    = (const float*)d_in[32];

    float* out = (float*)d_out;
    const float* h0 = state_h;            // state_h[0]
    const float* h1 = state_h + BR;       // state_h[1] (prev_h)
    float* h_att = out + BR;              // h_att output slot, reused as GEMM input
    float* scg  = out;                    // scratch in out slot 0 (rewritten by final lstm4)

    const bool big = ws_size >= 52428800ull;
    const int gslots = big ? 4 : 2;
    _Float16* g16 = (_Float16*)d_ws;                         // [gslots][1024][4096] f16
    _Float16* q16 = g16 + (size_t)gslots * 4ull * BR;        // [2][1024][1536] f16
    float*    a32 = (float*)(q16 + 2ull * 1536 * 1024);      // [3][1024][1024] f32
    float* a_attr = a32;
    float* a_obj  = a32 + BR;
    float* a_rela = a32 + 2 * BR;

    dim3 blk(256);
    const int zsplit = big ? 4 : 2;

    // 1) att-LSTM gates: A = [h1 | fc | xt | h0], K=4096, XCD-swizzled flat grid
    gemm_hf_swz<<<dim3(256 * zsplit), blk, 0, stream>>>(
        h1, fc, xt, h0, h0, att_Wih, att_Whh, att_Whh,
        3072, 3072, 1024, g16, 4096, 4096 / zsplit, zsplit);
    // 2) att-LSTM elementwise -> h_att (out[BR]), c_att (out[3BR])
    lstm4<<<dim3(4096), blk, 0, stream>>>(
        g16, 4ull * BR, gslots, att_bih, att_bhh, state_c,
        h_att, nullptr, out + 3 * BR);
    // 3) fused q = h_att @ [Wq_attr;Wq_obj;Wq_rela]^T, N=1536, K=1024 split 2x512
    gemm_hf<<<dim3(12, 8, 2), blk, 0, stream>>>(
        h_att, h_att, h_att, h_att, h_att,
        attr_Wq, obj_Wq, rela_Wq, 0, 1024, 1024, 1,
        q16, 1536, 512, 0);
    // 4a) scores: one wave per (b,row)
    att_scores<<<dim3(29696), blk, 0, stream>>>(
        p_attr, p_obj, p_rela, q16,
        attr_bq, obj_bq, rela_bq, attr_wa, obj_wa, rela_wa,
        attr_ba, obj_ba, rela_ba, scg);
    // 4b) softmax + weighted sums (fused)
    att_wsum<<<dim3(3072), blk, 0, stream>>>(
        attr_feats, obj_feats, rela_feats,
        attr_masks, att_masks, rela_masks, scg, a32);
    // 5) lang-LSTM gates: A = [h_att | a_attr | a_obj | a_rela | h1], K=5120, swizzled
    gemm_hf_swz<<<dim3(256 * zsplit), blk, 0, stream>>>(
        h_att, a_attr, a_obj, a_rela, h1,
        lang_Wih, lang_Whh, lang_Whh, 4096, 4096, 1024,
        g16, 4096, 5120 / zsplit, zsplit);
    // 6) lang-LSTM elementwise -> output (out[0]), h_lang (out[2BR]), c_lang (out[4BR])
    lstm4<<<dim3(4096), blk, 0, stream>>>(
        g16, 4ull * BR, gslots, lang_bih, lang_bhh, state_c + BR,
        out, out + 2 * BR, out + 4 * BR);
}